// Round 1
// baseline (293.943 us; speedup 1.0000x reference)
//
#include <hip/hip_runtime.h>
#include <hip/hip_bf16.h>
#include <math.h>

#define ENC2 1024
#define DECD 1024
#define ATT 512
#define NBATCH 32
#define SEQ 2048
#define MTOT (NBATCH*SEQ)

#define BM 128
#define BN 128
#define BK 32
#define LDK 40   // padded LDS row stride in bf16 elems (80 B -> 2-way bank alias, free)

typedef __attribute__((ext_vector_type(8))) short short8;
typedef __attribute__((ext_vector_type(4))) short short4v;
typedef __attribute__((ext_vector_type(4))) float f32x4;

static __device__ __forceinline__ short f2bf(float f) {
  union { float f; unsigned u; } x; x.f = f;
  unsigned r = (x.u + 0x7fffu + ((x.u >> 16) & 1u)) >> 16;  // RNE
  return (short)r;
}

// ---- U_w [ENC2][ATT] f32  ->  U_wT [ATT][ENC2] bf16 (LDS tile transpose) ----
__global__ __launch_bounds__(256) void uwT_kernel(const float* __restrict__ U_w,
                                                  short* __restrict__ U_wT) {
  __shared__ float tile[64][65];
  const int kt = blockIdx.x >> 3;    // 16 k-tiles
  const int ct = blockIdx.x & 7;     // 8 c-tiles
  const int k0 = kt * 64, c0 = ct * 64;
  const int t = threadIdx.x;
  const int r = t >> 4, cc = (t & 15) * 4;
  #pragma unroll
  for (int p = 0; p < 4; p++) {
    float4 v = *(const float4*)(U_w + (size_t)(k0 + r + p*16) * ATT + c0 + cc);
    tile[r + p*16][cc+0] = v.x; tile[r + p*16][cc+1] = v.y;
    tile[r + p*16][cc+2] = v.z; tile[r + p*16][cc+3] = v.w;
  }
  __syncthreads();
  const int cr = t >> 4, kk = (t & 15) * 4;
  #pragma unroll
  for (int p = 0; p < 4; p++) {
    int c = cr + p*16;
    short4v o;
    #pragma unroll
    for (int i = 0; i < 4; i++) o[i] = f2bf(tile[kk + i][c]);
    *(short4v*)(U_wT + (size_t)(c0 + c) * ENC2 + k0 + kk) = o;
  }
}

// ---- Wsb[b][a] = dh[b]·W_w[:,a] + W_b[a] + U_b[a]  (f32 exact) ----
__global__ __launch_bounds__(512) void ws_kernel(const float* __restrict__ dh,
                                                 const float* __restrict__ W_w,
                                                 const float* __restrict__ W_b,
                                                 const float* __restrict__ U_b,
                                                 float* __restrict__ Wsb) {
  const int b = blockIdx.x;
  const int a = threadIdx.x;
  const float* d = dh + b * DECD;
  float s = 0.f;
  #pragma unroll 4
  for (int k = 0; k < DECD; k++) s = fmaf(d[k], W_w[(size_t)k * ATT + a], s);
  Wsb[b * ATT + a] = s + W_b[a] + U_b[a];
}

// ---- main: energy[row] += sum_a v[a]*tanh(enc[row]·U[:,a] + Wsb[b][a]) ----
__global__ __launch_bounds__(256) void energy_kernel(
    const float* __restrict__ A,      // encoder [MTOT][ENC2] f32
    const short* __restrict__ Bt,     // U_wT [ATT][ENC2] bf16
    const float* __restrict__ Wsb,    // [NBATCH][ATT]
    const float* __restrict__ vw,     // [ATT]
    float* __restrict__ energy)       // [MTOT], pre-zeroed
{
  __shared__ __align__(16) short As[2][BM * LDK];
  __shared__ __align__(16) short Bs[2][BN * LDK];

  const int tid  = threadIdx.x;
  const int nt   = blockIdx.x & 3;    // n varies fastest -> A-tile L3 reuse
  const int mt   = blockIdx.x >> 2;
  const int row0 = mt * BM;
  const int col0 = nt * BN;
  const int bidx = row0 / SEQ;        // BM=128 divides SEQ -> single batch/block

  const int lane = tid & 63;
  const int wm   = (tid >> 7) & 1;
  const int wn   = (tid >> 6) & 1;

  const int ar = tid >> 3;            // A staging: 32 rows/pass, 128B/row
  const int ak = (tid & 7) * 4;
  const int bc = tid >> 2;            // B staging: 64 cols/pass, 64B/col
  const int bk = (tid & 3) * 8;

  const int fr = lane & 15;
  const int k0 = (lane >> 4) * 8;

  f32x4 acc[4][4];
  #pragma unroll
  for (int m = 0; m < 4; m++)
    #pragma unroll
    for (int n = 0; n < 4; n++) acc[m][n] = (f32x4){0.f, 0.f, 0.f, 0.f};

  float4 aRegs[4];
  short8 bRegs[2];
  const float* Abase = A + (size_t)row0 * ENC2;
  const short* Bbase = Bt + (size_t)col0 * ENC2;

  // prologue: stage kt=0
  #pragma unroll
  for (int p = 0; p < 4; p++)
    aRegs[p] = *(const float4*)(Abase + (size_t)(ar + p*32) * ENC2 + ak);
  #pragma unroll
  for (int p = 0; p < 2; p++)
    bRegs[p] = *(const short8*)(Bbase + (size_t)(bc + p*64) * ENC2 + bk);
  #pragma unroll
  for (int p = 0; p < 4; p++) {
    short4v o;
    o[0] = f2bf(aRegs[p].x); o[1] = f2bf(aRegs[p].y);
    o[2] = f2bf(aRegs[p].z); o[3] = f2bf(aRegs[p].w);
    *(short4v*)(&As[0][(ar + p*32) * LDK + ak]) = o;
  }
  #pragma unroll
  for (int p = 0; p < 2; p++)
    *(short8*)(&Bs[0][(bc + p*64) * LDK + bk]) = bRegs[p];
  __syncthreads();

  const int NT = ENC2 / BK;  // 32
  for (int kt = 0; kt < NT; kt++) {
    const int cur = kt & 1;
    const bool more = (kt + 1 < NT);
    if (more) {  // issue next-tile global loads early; latency hides under MFMAs
      const float* Ab = Abase + (kt + 1) * BK;
      #pragma unroll
      for (int p = 0; p < 4; p++)
        aRegs[p] = *(const float4*)(Ab + (size_t)(ar + p*32) * ENC2 + ak);
      const short* Bb = Bbase + (kt + 1) * BK;
      #pragma unroll
      for (int p = 0; p < 2; p++)
        bRegs[p] = *(const short8*)(Bb + (size_t)(bc + p*64) * ENC2 + bk);
    }
    short8 af[4], bfr[4];
    #pragma unroll
    for (int m = 0; m < 4; m++)
      af[m] = *(const short8*)(&As[cur][(wm*64 + m*16 + fr) * LDK + k0]);
    #pragma unroll
    for (int n = 0; n < 4; n++)
      bfr[n] = *(const short8*)(&Bs[cur][(wn*64 + n*16 + fr) * LDK + k0]);
    #pragma unroll
    for (int m = 0; m < 4; m++)
      #pragma unroll
      for (int n = 0; n < 4; n++)
        acc[m][n] = __builtin_amdgcn_mfma_f32_16x16x32_bf16(af[m], bfr[n], acc[m][n], 0, 0, 0);
    if (more) {
      #pragma unroll
      for (int p = 0; p < 4; p++) {
        short4v o;
        o[0] = f2bf(aRegs[p].x); o[1] = f2bf(aRegs[p].y);
        o[2] = f2bf(aRegs[p].z); o[3] = f2bf(aRegs[p].w);
        *(short4v*)(&As[cur ^ 1][(ar + p*32) * LDK + ak]) = o;
      }
      #pragma unroll
      for (int p = 0; p < 2; p++)
        *(short8*)(&Bs[cur ^ 1][(bc + p*64) * LDK + bk]) = bRegs[p];
    }
    __syncthreads();
  }

  // epilogue: tanh + v-dot + cross-lane (col) reduce + atomic partial add
  float vv[4], wsb[4];
  #pragma unroll
  for (int n = 0; n < 4; n++) {
    const int gc = col0 + wn*64 + n*16 + fr;
    vv[n]  = vw[gc];
    wsb[n] = Wsb[bidx * ATT + gc];
  }
  const int rg = lane >> 4;
  #pragma unroll
  for (int m = 0; m < 4; m++) {
    float part[4] = {0.f, 0.f, 0.f, 0.f};
    #pragma unroll
    for (int n = 0; n < 4; n++) {
      #pragma unroll
      for (int r = 0; r < 4; r++)
        part[r] += vv[n] * tanhf(acc[m][n][r] + wsb[n]);
    }
    #pragma unroll
    for (int r = 0; r < 4; r++) {
      float p = part[r];
      p += __shfl_xor(p, 1);
      p += __shfl_xor(p, 2);
      p += __shfl_xor(p, 4);
      p += __shfl_xor(p, 8);
      if (fr == 0) atomicAdd(&energy[row0 + wm*64 + m*16 + rg*4 + r], p);
    }
  }
}

// ---- softmax over S=2048 per batch row ----
__global__ __launch_bounds__(256) void softmax_kernel(const float* __restrict__ energy,
                                                      float* __restrict__ out) {
  __shared__ float redmax[4];
  __shared__ float redsum[4];
  const int b = blockIdx.x, t = threadIdx.x;
  const float* e = energy + b * SEQ;
  float vals[8];
  float mx = -1e30f;
  #pragma unroll
  for (int i = 0; i < 8; i++) { vals[i] = e[t + i*256]; mx = fmaxf(mx, vals[i]); }
  #pragma unroll
  for (int off = 1; off < 64; off <<= 1) mx = fmaxf(mx, __shfl_xor(mx, off));
  if ((t & 63) == 0) redmax[t >> 6] = mx;
  __syncthreads();
  mx = fmaxf(fmaxf(redmax[0], redmax[1]), fmaxf(redmax[2], redmax[3]));
  float sum = 0.f;
  #pragma unroll
  for (int i = 0; i < 8; i++) { vals[i] = expf(vals[i] - mx); sum += vals[i]; }
  #pragma unroll
  for (int off = 1; off < 64; off <<= 1) sum += __shfl_xor(sum, off);
  if ((t & 63) == 0) redsum[t >> 6] = sum;
  __syncthreads();
  const float inv = 1.f / (redsum[0] + redsum[1] + redsum[2] + redsum[3]);
  #pragma unroll
  for (int i = 0; i < 8; i++) out[b * SEQ + t + i*256] = vals[i] * inv;
}

extern "C" void kernel_launch(void* const* d_in, const int* in_sizes, int n_in,
                              void* d_out, int out_size, void* d_ws, size_t ws_size,
                              hipStream_t stream) {
  const float* dh  = (const float*)d_in[0];
  const float* enc = (const float*)d_in[1];
  const float* W_w = (const float*)d_in[2];
  const float* W_b = (const float*)d_in[3];
  const float* U_w = (const float*)d_in[4];
  const float* U_b = (const float*)d_in[5];
  const float* v_w = (const float*)d_in[6];
  float* out = (float*)d_out;

  char* ws = (char*)d_ws;
  float* energy = (float*)ws;                    // 256 KB
  float* Wsb    = (float*)(ws + 256 * 1024);     // 64 KB
  short* U_wT   = (short*)(ws + 320 * 1024);     // 1 MB

  hipMemsetAsync(energy, 0, MTOT * sizeof(float), stream);
  uwT_kernel<<<128, 256, 0, stream>>>(U_w, U_wT);
  ws_kernel<<<NBATCH, ATT, 0, stream>>>(dh, W_w, W_b, U_b, Wsb);
  energy_kernel<<<2048, 256, 0, stream>>>(enc, U_wT, Wsb, v_w, energy);
  softmax_kernel<<<NBATCH, 256, 0, stream>>>(energy, out);
}

// Round 3
// 154.429 us; speedup vs baseline: 1.9034x; 1.9034x over previous
//
#include <hip/hip_runtime.h>
#include <hip/hip_bf16.h>
#include <math.h>

#define ENC2 1024
#define DECD 1024
#define ATT 512
#define NBATCH 32
#define SEQ 2048
#define MTOT (NBATCH*SEQ)

#define BM 128
#define BN2 256
#define BK 32
#define LDK 40   // padded LDS row stride (80 B -> only 2-way bank alias, free per m136)

typedef __attribute__((ext_vector_type(8))) short short8;
typedef __attribute__((ext_vector_type(4))) short short4v;
typedef __attribute__((ext_vector_type(4))) float f32x4;

static __device__ __forceinline__ unsigned pk2(float a, float b) {
  __hip_bfloat162 h = __float22bfloat162_rn(float2{a, b});  // v_cvt_pk_bf16_f32 (RNE)
  union { __hip_bfloat162 h; unsigned u; } c; c.h = h;
  return c.u;
}

static __device__ __forceinline__ float fast_tanh(float x) {
  float ax = fabsf(x);
  float e = __expf(2.f * ax);          // overflow -> inf -> 2/inf = 0 -> t = 1 (correct)
  float t = 1.f - 2.f / (e + 1.f);
  return copysignf(t, x);
}

// ---- U_w [ENC2][ATT] f32  ->  U_wT [ATT][ENC2] bf16 (LDS tile transpose) ----
__global__ __launch_bounds__(256) void uwT_kernel(const float* __restrict__ U_w,
                                                  short* __restrict__ U_wT) {
  __shared__ float tile[64][65];
  const int kt = blockIdx.x >> 3;    // 16 k-tiles
  const int ct = blockIdx.x & 7;     // 8 c-tiles
  const int k0 = kt * 64, c0 = ct * 64;
  const int t = threadIdx.x;
  const int r = t >> 4, cc = (t & 15) * 4;
  #pragma unroll
  for (int p = 0; p < 4; p++) {
    float4 v = *(const float4*)(U_w + (size_t)(k0 + r + p*16) * ATT + c0 + cc);
    tile[r + p*16][cc+0] = v.x; tile[r + p*16][cc+1] = v.y;
    tile[r + p*16][cc+2] = v.z; tile[r + p*16][cc+3] = v.w;
  }
  __syncthreads();
  const int cr = t >> 4, kk = (t & 15) * 4;
  #pragma unroll
  for (int p = 0; p < 4; p++) {
    int c = cr + p*16;
    unsigned u0 = pk2(tile[kk + 0][c], tile[kk + 1][c]);
    unsigned u1 = pk2(tile[kk + 2][c], tile[kk + 3][c]);
    union { short4v s; unsigned u[2]; } o; o.u[0] = u0; o.u[1] = u1;
    *(short4v*)(U_wT + (size_t)(c0 + c) * ENC2 + k0 + kk) = o.s;
  }
}

// ---- Wsb[b][a] = dh[b]·W_w[:,a] + W_b[a] + U_b[a]  (f32, K-split x4) ----
__global__ __launch_bounds__(512) void ws_kernel(const float* __restrict__ dh,
                                                 const float* __restrict__ W_w,
                                                 const float* __restrict__ W_b,
                                                 const float* __restrict__ U_b,
                                                 float* __restrict__ Wsb) {
  __shared__ float dsh[DECD];
  __shared__ float part[4][ATT];
  const int b = blockIdx.x;
  const int t = threadIdx.x;
  for (int i = t; i < DECD; i += 512) dsh[i] = dh[(size_t)b * DECD + i];
  __syncthreads();
  const int ks = t >> 7;               // 0..3: k-slice of 256
  const int a4 = (t & 127) * 4;        // 4 attention cols per thread
  const float* wp = W_w + (size_t)(ks * 256) * ATT + a4;
  float4 s = {0.f, 0.f, 0.f, 0.f};
  #pragma unroll 8
  for (int k = 0; k < 256; k++) {
    float4 wv = *(const float4*)(wp + (size_t)k * ATT);
    float d = dsh[ks * 256 + k];
    s.x = fmaf(d, wv.x, s.x); s.y = fmaf(d, wv.y, s.y);
    s.z = fmaf(d, wv.z, s.z); s.w = fmaf(d, wv.w, s.w);
  }
  *(float4*)&part[ks][a4] = s;
  __syncthreads();
  if (t < ATT) {
    float v = part[0][t] + part[1][t] + part[2][t] + part[3][t];
    Wsb[(size_t)b * ATT + t] = v + W_b[t] + U_b[t];
  }
}

// ---- main: epart[nt][row] = sum_{a in nt-half} v[a]*tanh(enc[row]·U[:,a] + Wsb[b][a]) ----
__global__ __launch_bounds__(512) void energy_kernel(
    const float* __restrict__ A,      // encoder [MTOT][ENC2] f32
    const short* __restrict__ Bt,     // U_wT [ATT][ENC2] bf16
    const float* __restrict__ Wsb,    // [NBATCH][ATT]
    const float* __restrict__ vw,     // [ATT]
    float* __restrict__ epart)        // [2][MTOT]
{
  __shared__ __align__(16) short As[2][BM * LDK];
  __shared__ __align__(16) short Bs[2][BN2 * LDK];
  __shared__ float eps[4][BM];        // per-wn-wave partial energies

  const int tid = threadIdx.x;
  const int bid = blockIdx.x;
  // XCD-pairing swizzle: bids 16g+j and 16g+j+8 share mt (same A rows) and
  // have equal bid%8 -> same XCD -> A fetched once per pair from HBM.
  const int mt = (bid >> 4) * 8 + (bid & 7);   // 0..511
  const int nt = (bid >> 3) & 1;               // pair member
  const int row0 = mt * BM;
  const int col0 = nt * BN2;
  const int bidx = row0 / SEQ;

  const int lane = tid & 63;
  const int wid  = tid >> 6;
  const int wm   = wid >> 2;    // 0..1
  const int wn   = wid & 3;     // 0..3

  const int ar = tid >> 2, ak = (tid & 3) * 8;   // A staging: 128 rows, 4 thr/row, 8 f32 each
  const int bc = tid >> 1, bk = (tid & 1) * 16;  // B staging: 256 cols, 2 thr/col, 16 bf16 each

  const int fr = lane & 15;
  const int k0 = (lane >> 4) * 8;

  f32x4 acc[4][4];
  #pragma unroll
  for (int m = 0; m < 4; m++)
    #pragma unroll
    for (int n = 0; n < 4; n++) acc[m][n] = (f32x4){0.f, 0.f, 0.f, 0.f};

  const float* Abase = A + (size_t)row0 * ENC2;
  const short* Bbase = Bt + (size_t)col0 * ENC2;

  float4 aR0, aR1;
  short8 bR0, bR1;

  // prologue: stage kt=0
  aR0 = *(const float4*)(Abase + (size_t)ar * ENC2 + ak);
  aR1 = *(const float4*)(Abase + (size_t)ar * ENC2 + ak + 4);
  bR0 = *(const short8*)(Bbase + (size_t)bc * ENC2 + bk);
  bR1 = *(const short8*)(Bbase + (size_t)bc * ENC2 + bk + 8);
  {
    union { short8 s; unsigned u[4]; } w;
    w.u[0] = pk2(aR0.x, aR0.y); w.u[1] = pk2(aR0.z, aR0.w);
    w.u[2] = pk2(aR1.x, aR1.y); w.u[3] = pk2(aR1.z, aR1.w);
    *(short8*)(&As[0][ar * LDK + ak]) = w.s;
    *(short8*)(&Bs[0][bc * LDK + bk]) = bR0;
    *(short8*)(&Bs[0][bc * LDK + bk + 8]) = bR1;
  }
  __syncthreads();

  const int NT = ENC2 / BK;  // 32
  for (int kt = 0; kt < NT; kt++) {
    const int cur = kt & 1;
    const bool more = (kt + 1 < NT);
    if (more) {  // issue next-tile global loads; latency hides under ds_read+MFMA
      const float* Ab = Abase + (kt + 1) * BK;
      aR0 = *(const float4*)(Ab + (size_t)ar * ENC2 + ak);
      aR1 = *(const float4*)(Ab + (size_t)ar * ENC2 + ak + 4);
      const short* Bb = Bbase + (kt + 1) * BK;
      bR0 = *(const short8*)(Bb + (size_t)bc * ENC2 + bk);
      bR1 = *(const short8*)(Bb + (size_t)bc * ENC2 + bk + 8);
    }
    short8 af[4], bfr[4];
    #pragma unroll
    for (int m = 0; m < 4; m++)
      af[m] = *(const short8*)(&As[cur][(wm*64 + m*16 + fr) * LDK + k0]);
    #pragma unroll
    for (int n = 0; n < 4; n++)
      bfr[n] = *(const short8*)(&Bs[cur][(wn*64 + n*16 + fr) * LDK + k0]);
    #pragma unroll
    for (int m = 0; m < 4; m++)
      #pragma unroll
      for (int n = 0; n < 4; n++)
        acc[m][n] = __builtin_amdgcn_mfma_f32_16x16x32_bf16(af[m], bfr[n], acc[m][n], 0, 0, 0);
    if (more) {
      union { short8 s; unsigned u[4]; } w;
      w.u[0] = pk2(aR0.x, aR0.y); w.u[1] = pk2(aR0.z, aR0.w);
      w.u[2] = pk2(aR1.x, aR1.y); w.u[3] = pk2(aR1.z, aR1.w);
      *(short8*)(&As[cur ^ 1][ar * LDK + ak]) = w.s;
      *(short8*)(&Bs[cur ^ 1][bc * LDK + bk]) = bR0;
      *(short8*)(&Bs[cur ^ 1][bc * LDK + bk + 8]) = bR1;
    }
    __syncthreads();
  }

  // epilogue: tanh + v-dot; reduce across fr lanes (cols within wave), then
  // across the 4 wn-waves via LDS (fixes R1's last-writer-wins race).
  float vv[4], wsb[4];
  #pragma unroll
  for (int n = 0; n < 4; n++) {
    const int gc = col0 + wn*64 + n*16 + fr;
    vv[n]  = vw[gc];
    wsb[n] = Wsb[(size_t)bidx * ATT + gc];
  }
  const int rg = lane >> 4;
  #pragma unroll
  for (int m = 0; m < 4; m++) {
    float part[4] = {0.f, 0.f, 0.f, 0.f};
    #pragma unroll
    for (int n = 0; n < 4; n++) {
      #pragma unroll
      for (int r = 0; r < 4; r++)
        part[r] += vv[n] * fast_tanh(acc[m][n][r] + wsb[n]);
    }
    #pragma unroll
    for (int r = 0; r < 4; r++) {
      float p = part[r];
      p += __shfl_xor(p, 1);
      p += __shfl_xor(p, 2);
      p += __shfl_xor(p, 4);
      p += __shfl_xor(p, 8);
      if (fr == 0) eps[wn][wm*64 + m*16 + rg*4 + r] = p;
    }
  }
  __syncthreads();
  if (tid < BM) {
    float s = eps[0][tid] + eps[1][tid] + eps[2][tid] + eps[3][tid];
    epart[(size_t)nt * MTOT + row0 + tid] = s;
  }
}

// ---- softmax over S=2048 per batch row (sums the 2 partials) ----
__global__ __launch_bounds__(256) void softmax_kernel(const float* __restrict__ epart,
                                                      float* __restrict__ out) {
  __shared__ float redmax[4];
  __shared__ float redsum[4];
  const int b = blockIdx.x, t = threadIdx.x;
  const float* e0 = epart + (size_t)b * SEQ;
  const float* e1 = epart + (size_t)MTOT + (size_t)b * SEQ;
  float vals[8];
  float mx = -1e30f;
  #pragma unroll
  for (int i = 0; i < 8; i++) {
    vals[i] = e0[t + i*256] + e1[t + i*256];
    mx = fmaxf(mx, vals[i]);
  }
  #pragma unroll
  for (int off = 1; off < 64; off <<= 1) mx = fmaxf(mx, __shfl_xor(mx, off));
  if ((t & 63) == 0) redmax[t >> 6] = mx;
  __syncthreads();
  mx = fmaxf(fmaxf(redmax[0], redmax[1]), fmaxf(redmax[2], redmax[3]));
  float sum = 0.f;
  #pragma unroll
  for (int i = 0; i < 8; i++) { vals[i] = expf(vals[i] - mx); sum += vals[i]; }
  #pragma unroll
  for (int off = 1; off < 64; off <<= 1) sum += __shfl_xor(sum, off);
  if ((t & 63) == 0) redsum[t >> 6] = sum;
  __syncthreads();
  const float inv = 1.f / (redsum[0] + redsum[1] + redsum[2] + redsum[3]);
  #pragma unroll
  for (int i = 0; i < 8; i++) out[(size_t)b * SEQ + t + i*256] = vals[i] * inv;
}

extern "C" void kernel_launch(void* const* d_in, const int* in_sizes, int n_in,
                              void* d_out, int out_size, void* d_ws, size_t ws_size,
                              hipStream_t stream) {
  const float* dh  = (const float*)d_in[0];
  const float* enc = (const float*)d_in[1];
  const float* W_w = (const float*)d_in[2];
  const float* W_b = (const float*)d_in[3];
  const float* U_w = (const float*)d_in[4];
  const float* U_b = (const float*)d_in[5];
  const float* v_w = (const float*)d_in[6];
  float* out = (float*)d_out;

  char* ws = (char*)d_ws;
  float* epart = (float*)ws;                      // 512 KB (2 x MTOT f32)
  float* Wsb   = (float*)(ws + 512 * 1024);       // 64 KB
  short* U_wT  = (short*)(ws + 576 * 1024);       // 1 MB

  uwT_kernel<<<128, 256, 0, stream>>>(U_w, U_wT);
  ws_kernel<<<NBATCH, 512, 0, stream>>>(dh, W_w, W_b, U_b, Wsb);
  energy_kernel<<<1024, 512, 0, stream>>>(enc, U_wT, Wsb, v_w, epart);
  softmax_kernel<<<NBATCH, 256, 0, stream>>>(epart, out);
}